// Round 4
// baseline (121.779 us; speedup 1.0000x reference)
//
#include <hip/hip_runtime.h>
#include <math.h>

#define L 2048
#define B 4
#define QH 32
#define KVH 8
#define G 4
#define D 128
#define NS (B*KVH)   /* 32 kv streams */
#define WS 12
#define MASK_CONST -50000.0f
#define EPS_F 1.1920929e-07f

#define NQ_BLOCKS   32768   /* L*B*QH*D/4 float4 / 256 threads */
#define NPOOL_BLOCKS 16384  /* L*NS pairs / 4 waves per block */
#define NMASK_BLOCKS 1024   /* L*B*QH / 256 */

typedef float f32x4 __attribute__((ext_vector_type(4)));

// Single fused kernel: qcopy (blocks [0,NQ)), pool (blocks [NQ,NQ+NPOOL)), mask (rest).
// No prep pass: each pool wave computes its own gates/weights in a 1-load-per-lane
// prologue (48 lanes: q ch-127 for 12 sources x 4 grouped heads; 11 lanes: k ch-127
// gate decisions), combined via shfl_xor segmented sum + uniform shfl broadcasts.
__global__ void fused_kernel(const f32x4* __restrict__ q4,
                             const float* __restrict__ q,
                             const float* __restrict__ k, const float* __restrict__ v,
                             f32x4* __restrict__ outq4,
                             float* __restrict__ k2, float* __restrict__ v2,
                             float* __restrict__ mask) {
    int bid = blockIdx.x;
    if (bid < NQ_BLOCKS) {
        // ---- q copy, zero channel D-1, streaming (nontemporal) ----
        size_t i = (size_t)bid * 256 + threadIdx.x;
        f32x4 val = __builtin_nontemporal_load(&q4[i]);
        if ((i & (D / 4 - 1)) == (D / 4 - 1)) val.w = 0.0f;
        __builtin_nontemporal_store(val, &outq4[i]);
    } else if (bid < NQ_BLOCKS + NPOOL_BLOCKS) {
        // ---- pooling + GQA-expanded k2/v2 ----
        int pb   = bid - NQ_BLOCKS;
        int grp  = threadIdx.x >> 6;           // 4 waves per block
        int lane = threadIdx.x & 63;
        int pair = pb * 4 + grp;               // (t,n) index
        int n = pair & (NS - 1);
        int t = pair >> 5;                     // pair / NS
        int b = n >> 3, h = n & 7;

        // Prologue: one scattered load per lane.
        //   lanes 0..47 : j=lane>>2 (source age), g=lane&3 (grouped head);
        //                 after 2x shfl_xor + sigmoid, lane 4j holds w[t-j].
        //   lanes 48..58: jj=lane-48; dec[t-jj] in {0,1}  (gate for j=jj+1).
        float pv = 0.0f;
        if (lane < 48) {
            int j = lane >> 2, g = lane & 3;
            int s = t - j;
            if (s >= 0)
                pv = q[(((size_t)s * B + b) * QH + h * G + g) * D + (D - 1)];
            pv += __shfl_xor(pv, 1);
            pv += __shfl_xor(pv, 2);           // 4-lane segment sum (group mean*4)
            pv = 1.0f / (1.0f + __expf(-(pv * 0.25f + 2.0f))) + EPS_F;
        } else if (lane < 48 + WS - 1) {
            int u = t - (lane - 48);           // dec index s+1 for j=lane-47
            float kv = (u >= 0) ? k[((size_t)u * NS + n) * D + (D - 1)] : 3.0f;
            pv = (kv > 2.0f) ? 1.0f : 0.0f;
        }

        int c = lane * 4;                      // channel in concat [0,256)
        const bool is_k = (c < D);
        const float* base = is_k ? k : v;
        int coff = is_k ? c : (c - D);

        float ax = 0.f, ay = 0.f, az = 0.f, aw = 0.f, den = 0.f;
        for (int j = 0; j < WS; ++j) {
            int s = t - j;
            if (s < 0) break;
            if (j > 0) {
                float d = __shfl(pv, 47 + j);  // dec[s+1]; product==0 iff any 0
                if (d == 0.0f) break;          // wave-uniform break
            }
            float w = __shfl(pv, 4 * j);       // wts[s]
            const f32x4 x = *reinterpret_cast<const f32x4*>(base + ((size_t)s * NS + n) * D + coff);
            ax += w * x.x; ay += w * x.y; az += w * x.z; aw += w * x.w;
            den += w;
        }
        f32x4 o;
        o.x = ax / den; o.y = ay / den; o.z = az / den; o.w = aw / den;

        size_t head0 = (((size_t)t * B + b) * QH + h * G) * D;   // first of 4 GQA heads
        if (is_k) {
            if (c == D - 4) o.w = 0.0f;        // zero pooled-k channel 127
            f32x4* dst = reinterpret_cast<f32x4*>(k2) + (head0 + c) / 4;
            __builtin_nontemporal_store(o, dst);
            __builtin_nontemporal_store(o, dst + D / 4);
            __builtin_nontemporal_store(o, dst + 2 * (D / 4));
            __builtin_nontemporal_store(o, dst + 3 * (D / 4));
        } else {
            f32x4* dst = reinterpret_cast<f32x4*>(v2) + (head0 + (c - D)) / 4;
            __builtin_nontemporal_store(o, dst);
            __builtin_nontemporal_store(o, dst + D / 4);
            __builtin_nontemporal_store(o, dst + 2 * (D / 4));
            __builtin_nontemporal_store(o, dst + 3 * (D / 4));
        }
    } else {
        // ---- mask: dec computed directly from k channel 127 ----
        int idx = (bid - NQ_BLOCKS - NPOOL_BLOCKS) * 256 + threadIdx.x;
        int qh = idx & (QH - 1);
        int b = (idx >> 5) & (B - 1);
        int t = idx >> 7;
        float m = 0.0f;
        if (t < L - 1) {
            int n = b * KVH + (qh >> 2);
            float kv = k[((size_t)(t + 1) * NS + n) * D + (D - 1)];
            m = (kv > 2.0f) ? MASK_CONST : 0.0f;
        }
        mask[idx] = m;
    }
}

extern "C" void kernel_launch(void* const* d_in, const int* in_sizes, int n_in,
                              void* d_out, int out_size, void* d_ws, size_t ws_size,
                              hipStream_t stream) {
    const float* q = (const float*)d_in[0];   // (L,B,QH,D)
    const float* k = (const float*)d_in[1];   // (L,B,KVH,D)
    const float* v = (const float*)d_in[2];   // (L,B,KVH,D)

    float* out_q    = (float*)d_out;                          // 33,554,432
    float* out_k2   = out_q  + (size_t)L * B * QH * D;        // 33,554,432
    float* out_v2   = out_k2 + (size_t)L * B * QH * D;        // 33,554,432
    float* out_mask = out_v2 + (size_t)L * B * QH * D;        // 262,144

    int blocks = NQ_BLOCKS + NPOOL_BLOCKS + NMASK_BLOCKS;     // 50176
    fused_kernel<<<blocks, 256, 0, stream>>>(
        (const f32x4*)q, q, k, v,
        (f32x4*)out_q, out_k2, out_v2, out_mask);
}

// Round 5
// 104.578 us; speedup vs baseline: 1.1645x; 1.1645x over previous
//
#include <hip/hip_runtime.h>
#include <math.h>

#define L 2048
#define B 4
#define QH 32
#define KVH 8
#define G 4
#define D 128
#define NS (B*KVH)   /* 32 kv streams */
#define WS 12
#define MASK_CONST -50000.0f
#define EPS_F 1.1920929e-07f

#define NQ_BLOCKS   32768   /* L*B*QH*D/4 float4 / 256 threads */
#define NPOOL_BLOCKS 16384  /* (L/4)*NS : one block = 4 consecutive t, one n */
#define NMASK_BLOCKS 1024   /* L*B*QH / 256 */

typedef float f32x4 __attribute__((ext_vector_type(4)));

// Single fused kernel: qcopy (blocks [0,NQ)), pool (blocks [NQ,NQ+NPOOL)), mask (rest).
// Pool: one block = (n, t0..t0+3). Block prologue computes the 15 shared weights
// (60 scattered q ch-127 loads, one per thread, 4-head sum via shfl_xor) and the
// 14 shared gate decisions (k ch-127) into LDS, amortizing the scatter 4x per wave
// and removing the separate prep kernel.
__global__ void fused_kernel(const f32x4* __restrict__ q4,
                             const float* __restrict__ q,
                             const float* __restrict__ k, const float* __restrict__ v,
                             f32x4* __restrict__ outq4,
                             float* __restrict__ k2, float* __restrict__ v2,
                             float* __restrict__ mask) {
    int bid = blockIdx.x;
    if (bid < NQ_BLOCKS) {
        // ---- q copy, zero channel D-1, streaming (nontemporal) ----
        size_t i = (size_t)bid * 256 + threadIdx.x;
        f32x4 val = __builtin_nontemporal_load(&q4[i]);
        if ((i & (D / 4 - 1)) == (D / 4 - 1)) val.w = 0.0f;
        __builtin_nontemporal_store(val, &outq4[i]);
    } else if (bid < NQ_BLOCKS + NPOOL_BLOCKS) {
        // ---- pooling + GQA-expanded k2/v2 ----
        int pb = bid - NQ_BLOCKS;
        int n  = pb & (NS - 1);
        int t0 = (pb >> 5) * 4;                // block covers t0..t0+3
        int b = n >> 3, h = n & 7;
        int tid  = threadIdx.x;
        int grp  = tid >> 6;                   // wave -> t = t0 + grp
        int lane = tid & 63;

        __shared__ float s_w[15];              // w[s], s = t0-11+i
        __shared__ float s_dec[14];            // dec[u], u = t0-10+i

        if (tid < 60) {                        // wave 0: weights
            int i = tid >> 2, g = tid & 3;     // s = t0-11+i, grouped head g
            int s = t0 - 11 + i;
            float pv = 0.0f;
            if (s >= 0)
                pv = q[(((size_t)s * B + b) * QH + h * G + g) * D + (D - 1)];
            pv += __shfl_xor(pv, 1);
            pv += __shfl_xor(pv, 2);           // 4-head sum
            if (g == 0)
                s_w[i] = 1.0f / (1.0f + __expf(-(pv * 0.25f + 2.0f))) + EPS_F;
        } else if (tid >= 64 && tid < 78) {    // wave 1: gates
            int u = t0 - 10 + (tid - 64);
            float kv = (u >= 0) ? k[((size_t)u * NS + n) * D + (D - 1)] : 3.0f;
            s_dec[tid - 64] = (kv > 2.0f) ? 1.0f : 0.0f;
        }
        __syncthreads();

        int t = t0 + grp;
        int c = lane * 4;                      // channel in concat [0,256)
        const bool is_k = (c < D);
        const float* base = is_k ? k : v;
        int coff = is_k ? c : (c - D);

        float ax = 0.f, ay = 0.f, az = 0.f, aw = 0.f, den = 0.f;
        for (int j = 0; j < WS; ++j) {
            int s = t - j;
            if (s < 0) break;
            int wi = grp + 11 - j;             // shared index for both w[s] and dec[s+1]
            if (j > 0 && s_dec[wi] == 0.0f) break;   // wave-uniform break
            float w = s_w[wi];
            const f32x4 x = *reinterpret_cast<const f32x4*>(base + ((size_t)s * NS + n) * D + coff);
            ax += w * x.x; ay += w * x.y; az += w * x.z; aw += w * x.w;
            den += w;
        }
        f32x4 o;
        o.x = ax / den; o.y = ay / den; o.z = az / den; o.w = aw / den;

        size_t head0 = (((size_t)t * B + b) * QH + h * G) * D;   // first of 4 GQA heads
        if (is_k) {
            if (c == D - 4) o.w = 0.0f;        // zero pooled-k channel 127
            f32x4* dst = reinterpret_cast<f32x4*>(k2) + (head0 + c) / 4;
            __builtin_nontemporal_store(o, dst);
            __builtin_nontemporal_store(o, dst + D / 4);
            __builtin_nontemporal_store(o, dst + 2 * (D / 4));
            __builtin_nontemporal_store(o, dst + 3 * (D / 4));
        } else {
            f32x4* dst = reinterpret_cast<f32x4*>(v2) + (head0 + (c - D)) / 4;
            __builtin_nontemporal_store(o, dst);
            __builtin_nontemporal_store(o, dst + D / 4);
            __builtin_nontemporal_store(o, dst + 2 * (D / 4));
            __builtin_nontemporal_store(o, dst + 3 * (D / 4));
        }
    } else {
        // ---- mask: dec computed directly from k channel 127 ----
        int idx = (bid - NQ_BLOCKS - NPOOL_BLOCKS) * 256 + threadIdx.x;
        int qh = idx & (QH - 1);
        int b = (idx >> 5) & (B - 1);
        int t = idx >> 7;
        float m = 0.0f;
        if (t < L - 1) {
            int n = b * KVH + (qh >> 2);
            float kv = k[((size_t)(t + 1) * NS + n) * D + (D - 1)];
            m = (kv > 2.0f) ? MASK_CONST : 0.0f;
        }
        mask[idx] = m;
    }
}

extern "C" void kernel_launch(void* const* d_in, const int* in_sizes, int n_in,
                              void* d_out, int out_size, void* d_ws, size_t ws_size,
                              hipStream_t stream) {
    const float* q = (const float*)d_in[0];   // (L,B,QH,D)
    const float* k = (const float*)d_in[1];   // (L,B,KVH,D)
    const float* v = (const float*)d_in[2];   // (L,B,KVH,D)

    float* out_q    = (float*)d_out;                          // 33,554,432
    float* out_k2   = out_q  + (size_t)L * B * QH * D;        // 33,554,432
    float* out_v2   = out_k2 + (size_t)L * B * QH * D;        // 33,554,432
    float* out_mask = out_v2 + (size_t)L * B * QH * D;        // 262,144

    int blocks = NQ_BLOCKS + NPOOL_BLOCKS + NMASK_BLOCKS;     // 50176
    fused_kernel<<<blocks, 256, 0, stream>>>(
        (const f32x4*)q, q, k, v,
        (f32x4*)out_q, out_k2, out_v2, out_mask);
}

// Round 6
// 99.174 us; speedup vs baseline: 1.2279x; 1.0545x over previous
//
#include <hip/hip_runtime.h>
#include <math.h>

#define L 2048
#define B 4
#define QH 32
#define KVH 8
#define G 4
#define D 128
#define NS (B*KVH)   /* 32 kv streams */
#define WS 12
#define MASK_CONST -50000.0f
#define EPS_F 1.1920929e-07f

#define TBLK 16               /* t-values per pool block */
#define NPOOL_BLOCKS ((L/TBLK)*NS)          /* 4096 : one block = 16 t, one n */
#define NQ_BLOCKS   32768     /* L*B*QH*D/4 float4 / 256 threads */

typedef float f32x4 __attribute__((ext_vector_type(4)));

// Single fused kernel.
//  - pool blocks [0, NPOOL): one block = (n, t0..t0+15), 4 waves x 4 t each.
//    Prologue: 27 shared weights (108 scattered q ch-127 loads, 4-head sum via
//    shfl_xor) + 27 shared gate decisions (k ch-127) -> LDS; one __syncthreads.
//    Mask for the block's 16 t is written from s_dec (no separate mask pass).
//  - qcopy blocks [NPOOL, NPOOL+NQ): streaming q copy with ch-127 zeroed.
__global__ void fused_kernel(const f32x4* __restrict__ q4,
                             const float* __restrict__ q,
                             const float* __restrict__ k, const float* __restrict__ v,
                             f32x4* __restrict__ outq4,
                             float* __restrict__ k2, float* __restrict__ v2,
                             float* __restrict__ mask) {
    int bid = blockIdx.x;
    if (bid < NPOOL_BLOCKS) {
        // ---- pooling + GQA-expanded k2/v2 + mask ----
        int n  = bid & (NS - 1);
        int t0 = (bid >> 5) * TBLK;            // block covers t0..t0+15
        int b = n >> 3, h = n & 7;
        int tid  = threadIdx.x;
        int grp  = tid >> 6;
        int lane = tid & 63;

        __shared__ float s_w[27];              // w[s],  s = t0-11+i
        __shared__ float s_dec[27];            // dec[u], u = t0-10+i

        if (tid < 108) {                       // waves 0-1: weights (27 x 4 heads)
            int i = tid >> 2, g = tid & 3;
            int s = t0 - 11 + i;
            float pv = 0.0f;
            if (s >= 0)
                pv = q[(((size_t)s * B + b) * QH + h * G + g) * D + (D - 1)];
            pv += __shfl_xor(pv, 1);
            pv += __shfl_xor(pv, 2);           // 4-head sum (groups never cross wave)
            if (g == 0)
                s_w[i] = 1.0f / (1.0f + __expf(-(pv * 0.25f + 2.0f))) + EPS_F;
        } else if (tid >= 128 && tid < 155) {  // wave 2: gates
            int u = t0 - 10 + (tid - 128);
            float kv = (u >= 0 && u < L) ? k[((size_t)u * NS + n) * D + (D - 1)] : 3.0f;
            s_dec[tid - 128] = (kv > 2.0f) ? 1.0f : 0.0f;
        }
        __syncthreads();

        int c = lane * 4;                      // channel in concat [0,256)
        const bool is_k = (c < D);
        const float* base = is_k ? k : v;
        int coff = is_k ? c : (c - D);

        for (int it = 0; it < 4; ++it) {
            int lt = grp * 4 + it;             // local t index 0..15
            int t  = t0 + lt;

            float ax = 0.f, ay = 0.f, az = 0.f, aw = 0.f, den = 0.f;
            for (int j = 0; j < WS; ++j) {
                int s = t - j;
                if (s < 0) break;
                int wi = lt - j + 11;          // shared index for w[s] AND dec[s+1]
                if (j > 0 && s_dec[wi] == 0.0f) break;   // wave-uniform break
                float w = s_w[wi];
                const f32x4 x = *reinterpret_cast<const f32x4*>(base + ((size_t)s * NS + n) * D + coff);
                ax += w * x.x; ay += w * x.y; az += w * x.z; aw += w * x.w;
                den += w;
            }
            f32x4 o;
            o.x = ax / den; o.y = ay / den; o.z = az / den; o.w = aw / den;

            size_t head0 = (((size_t)t * B + b) * QH + h * G) * D;  // first of 4 GQA heads
            if (is_k) {
                if (c == D - 4) o.w = 0.0f;    // zero pooled-k channel 127
                f32x4* dst = reinterpret_cast<f32x4*>(k2) + (head0 + c) / 4;
                __builtin_nontemporal_store(o, dst);
                __builtin_nontemporal_store(o, dst + D / 4);
                __builtin_nontemporal_store(o, dst + 2 * (D / 4));
                __builtin_nontemporal_store(o, dst + 3 * (D / 4));
            } else {
                f32x4* dst = reinterpret_cast<f32x4*>(v2) + (head0 + (c - D)) / 4;
                __builtin_nontemporal_store(o, dst);
                __builtin_nontemporal_store(o, dst + D / 4);
                __builtin_nontemporal_store(o, dst + 2 * (D / 4));
                __builtin_nontemporal_store(o, dst + 3 * (D / 4));
            }
        }

        // ---- mask for this block's 16 t (4 GQA copies each) ----
        if (tid < TBLK * G) {
            int lt = tid >> 2, g = tid & 3;
            int t = t0 + lt;
            float m = (t < L - 1) ? s_dec[lt + 11] * MASK_CONST : 0.0f;
            mask[(size_t)t * B * QH + b * QH + h * G + g] = m;
        }
    } else {
        // ---- q copy, zero channel D-1, streaming (nontemporal) ----
        size_t i = (size_t)(bid - NPOOL_BLOCKS) * 256 + threadIdx.x;
        f32x4 val = __builtin_nontemporal_load(&q4[i]);
        if ((i & (D / 4 - 1)) == (D / 4 - 1)) val.w = 0.0f;
        __builtin_nontemporal_store(val, &outq4[i]);
    }
}

extern "C" void kernel_launch(void* const* d_in, const int* in_sizes, int n_in,
                              void* d_out, int out_size, void* d_ws, size_t ws_size,
                              hipStream_t stream) {
    const float* q = (const float*)d_in[0];   // (L,B,QH,D)
    const float* k = (const float*)d_in[1];   // (L,B,KVH,D)
    const float* v = (const float*)d_in[2];   // (L,B,KVH,D)

    float* out_q    = (float*)d_out;                          // 33,554,432
    float* out_k2   = out_q  + (size_t)L * B * QH * D;        // 33,554,432
    float* out_v2   = out_k2 + (size_t)L * B * QH * D;        // 33,554,432
    float* out_mask = out_v2 + (size_t)L * B * QH * D;        // 262,144

    int blocks = NPOOL_BLOCKS + NQ_BLOCKS;    // 36864
    fused_kernel<<<blocks, 256, 0, stream>>>(
        (const f32x4*)q, q, k, v,
        (f32x4*)out_q, out_k2, out_v2, out_mask);
}